// Round 1
// baseline (257.553 us; speedup 1.0000x reference)
//
#include <hip/hip_runtime.h>

// out[p][j] = L(j-1) - L(j), where L(e) = relu(1 - relu(x_full[e+1]-x)/(h[e]+1e-9)),
// L(-1)=1, L(n_elem)=0. L is a monotone staircase 1..0 with one fractional step at
// the interval e0 containing x, so each row is zero except:
//   out[e0]   = 1 - frac
//   out[e0+1] = frac
// with frac computed by the reference's exact formula on interval e0.
// Strategy: memset the 268.6 MB output to zero (write-BW bound), then one thread
// per eval point does a binary search in LDS and writes the 2 nonzeros.

__global__ void scatter_hats(const float* __restrict__ x_eval,
                             const float* __restrict__ x_full,
                             float* __restrict__ out,
                             int n_points, int n_nodes) {
    extern __shared__ float s_xf[];
    for (int i = threadIdx.x; i < n_nodes; i += blockDim.x) s_xf[i] = x_full[i];
    __syncthreads();

    int p = blockIdx.x * blockDim.x + threadIdx.x;
    if (p >= n_points) return;

    float x = x_eval[p];

    // upper_bound: first index with x_full[idx] > x
    int lo = 0, hi = n_nodes;
    while (lo < hi) {
        int mid = (lo + hi) >> 1;
        if (s_xf[mid] <= x) lo = mid + 1; else hi = mid;
    }
    int e0 = lo - 1;
    if (e0 < 0) e0 = 0;                 // x below all nodes -> row = [1,0,...]
    int emax = n_nodes - 2;
    if (e0 > emax) e0 = emax;           // x above all nodes -> row = [...,0,1]

    float xa = s_xf[e0];
    float xb = s_xf[e0 + 1];
    float l1   = fmaxf(xb - x, 0.0f);                         // relu(xb - x)
    float frac = fmaxf(1.0f - l1 / (xb - xa + 1e-9f), 0.0f);  // relu(1 - l1/(h+eps))

    size_t base = (size_t)p * (size_t)n_nodes;
    out[base + e0]     = 1.0f - frac;
    out[base + e0 + 1] = frac;
}

extern "C" void kernel_launch(void* const* d_in, const int* in_sizes, int n_in,
                              void* d_out, int out_size, void* d_ws, size_t ws_size,
                              hipStream_t stream) {
    const float* x_eval = (const float*)d_in[0];
    const float* x_full = (const float*)d_in[1];
    float* out = (float*)d_out;

    int n_points = in_sizes[0];   // 32768 (n_points x 1)
    int n_nodes  = in_sizes[1];   // 2049  (= output columns)

    // Zero the whole output (the only heavy memory traffic in this problem).
    hipMemsetAsync(d_out, 0, (size_t)out_size * sizeof(float), stream);

    int block = 256;
    int grid  = (n_points + block - 1) / block;
    size_t smem = (size_t)n_nodes * sizeof(float);
    scatter_hats<<<grid, block, smem, stream>>>(x_eval, x_full, out, n_points, n_nodes);
}